// Round 1
// baseline (213.069 us; speedup 1.0000x reference)
//
#include <hip/hip_runtime.h>

// RBF kernel layer: K[b,n,m] = exp(-max(|a|^2+|b|^2-2ab,0)/(2*sigma^2))
// A: (8,2048,128) f32 -> flat (16384,128); B: (4096,128) f32; out (16384,4096) f32.
// Strategy: bf16 split (hi+lo) 3-pass MFMA GEMM, K=128 fully LDS-resident,
// fused exp epilogue. Write-bound target ~41us floor.

typedef __attribute__((ext_vector_type(8))) short bf16x8;
typedef __attribute__((ext_vector_type(4))) float f32x4;

#define PK 136  // padded row stride in shorts (272 B = 17*16B, breaks bank alignment)

__device__ __forceinline__ short f2bf_hi(float x) {
    union { float f; unsigned u; } v; v.f = x;
    unsigned r = (v.u + 0x7fffu + ((v.u >> 16) & 1u)) >> 16;  // RN-even
    return (short)r;
}
__device__ __forceinline__ float bf2f(short h) {
    union { unsigned u; float f; } v; v.u = ((unsigned)(unsigned short)h) << 16;
    return v.f;
}

__global__ __launch_bounds__(256, 2)
void rbf_mfma_kernel(const float* __restrict__ A, const float* __restrict__ Bm,
                     const float* __restrict__ sigp, float* __restrict__ out) {
    __shared__ __align__(16) short sAhi[64 * PK];
    __shared__ __align__(16) short sAlo[64 * PK];
    __shared__ __align__(16) short sBhi[64 * PK];
    __shared__ __align__(16) short sBlo[64 * PK];
    __shared__ float nA[64];
    __shared__ float nB[64];

    const int tid  = threadIdx.x;
    const int brow = blockIdx.y << 6;   // 64-row tile of flattened A (16384 rows)
    const int bcol = blockIdx.x << 6;   // 64-row tile of B (4096 rows)

    // ---- Stage: global f32 -> LDS bf16 hi/lo, + row norms (f32-exact) ----
    const int r0 = tid >> 5;            // 0..7
    const int kq = (tid & 31) << 2;     // k offset, float4 granularity
#pragma unroll
    for (int it = 0; it < 8; ++it) {
        const int row = r0 + (it << 3);
        const float4 va = *(const float4*)(A  + (size_t)(brow + row) * 128 + kq);
        const float4 vb = *(const float4*)(Bm + (size_t)(bcol + row) * 128 + kq);

        short4 ha, la, hb, lb;
        ha.x = f2bf_hi(va.x); la.x = f2bf_hi(va.x - bf2f(ha.x));
        ha.y = f2bf_hi(va.y); la.y = f2bf_hi(va.y - bf2f(ha.y));
        ha.z = f2bf_hi(va.z); la.z = f2bf_hi(va.z - bf2f(ha.z));
        ha.w = f2bf_hi(va.w); la.w = f2bf_hi(va.w - bf2f(ha.w));
        hb.x = f2bf_hi(vb.x); lb.x = f2bf_hi(vb.x - bf2f(hb.x));
        hb.y = f2bf_hi(vb.y); lb.y = f2bf_hi(vb.y - bf2f(hb.y));
        hb.z = f2bf_hi(vb.z); lb.z = f2bf_hi(vb.z - bf2f(hb.z));
        hb.w = f2bf_hi(vb.w); lb.w = f2bf_hi(vb.w - bf2f(hb.w));

        const int idx = row * PK + kq;
        *(short4*)(&sAhi[idx]) = ha;
        *(short4*)(&sAlo[idx]) = la;
        *(short4*)(&sBhi[idx]) = hb;
        *(short4*)(&sBlo[idx]) = lb;

        float sa = va.x * va.x + va.y * va.y + va.z * va.z + va.w * va.w;
        float sb = vb.x * vb.x + vb.y * vb.y + vb.z * vb.z + vb.w * vb.w;
#pragma unroll
        for (int m = 16; m >= 1; m >>= 1) {
            sa += __shfl_xor(sa, m);
            sb += __shfl_xor(sb, m);
        }
        if ((tid & 31) == 0) { nA[row] = sa; nB[row] = sb; }
    }
    __syncthreads();

    // ---- Compute: 3-pass split MFMA (hi*hi + hi*lo + lo*hi), K=128 resident ----
    const int lane = tid & 63;
    const int w    = tid >> 6;
    const int wr   = (w >> 1) << 5;     // wave row base within tile: 0 or 32
    const int wc   = (w & 1) << 5;      // wave col base within tile: 0 or 32
    const int lr   = lane & 15;
    const int kb   = lane >> 4;         // k-block 0..3

    f32x4 acc[2][2] = {};

#pragma unroll
    for (int ks = 0; ks < 4; ++ks) {
        const int kc = (ks << 5) + (kb << 3);
        bf16x8 ahi[2], alo[2], bhi[2], blo[2];
#pragma unroll
        for (int i = 0; i < 2; ++i) {
            const int ar = (wr + (i << 4) + lr) * PK + kc;
            ahi[i] = *(const bf16x8*)(&sAhi[ar]);
            alo[i] = *(const bf16x8*)(&sAlo[ar]);
            const int br = (wc + (i << 4) + lr) * PK + kc;
            bhi[i] = *(const bf16x8*)(&sBhi[br]);
            blo[i] = *(const bf16x8*)(&sBlo[br]);
        }
#pragma unroll
        for (int i = 0; i < 2; ++i) {
#pragma unroll
            for (int j = 0; j < 2; ++j) {
                acc[i][j] = __builtin_amdgcn_mfma_f32_16x16x32_bf16(ahi[i], bhi[j], acc[i][j], 0, 0, 0);
                acc[i][j] = __builtin_amdgcn_mfma_f32_16x16x32_bf16(ahi[i], blo[j], acc[i][j], 0, 0, 0);
                acc[i][j] = __builtin_amdgcn_mfma_f32_16x16x32_bf16(alo[i], bhi[j], acc[i][j], 0, 0, 0);
            }
        }
    }

    // ---- Epilogue: dist2 -> exp, store f32 ----
    float sg = sigp[0];
    sg = fmaxf(sg, 0.001f);
    const float c = -0.5f / (sg * sg);

#pragma unroll
    for (int i = 0; i < 2; ++i) {
#pragma unroll
        for (int j = 0; j < 2; ++j) {
#pragma unroll
            for (int r = 0; r < 4; ++r) {
                const int lrow = wr + (i << 4) + (kb << 2) + r;  // D row = (lane>>4)*4+reg
                const int lcol = wc + (j << 4) + lr;             // D col = lane&15
                const float dot = acc[i][j][r];
                float d2 = nA[lrow] + nB[lcol] - 2.0f * dot;
                d2 = fmaxf(d2, 0.0f);
                out[(size_t)(brow + lrow) * 4096 + (bcol + lcol)] = __expf(d2 * c);
            }
        }
    }
}

extern "C" void kernel_launch(void* const* d_in, const int* in_sizes, int n_in,
                              void* d_out, int out_size, void* d_ws, size_t ws_size,
                              hipStream_t stream) {
    const float* A    = (const float*)d_in[0];   // (8,2048,128) -> (16384,128)
    const float* Bm   = (const float*)d_in[1];   // (4096,128)
    const float* sigp = (const float*)d_in[2];   // scalar
    float* out = (float*)d_out;                  // (16384,4096)

    dim3 grid(4096 / 64, 16384 / 64, 1);         // (64, 256)
    dim3 block(256, 1, 1);
    rbf_mfma_kernel<<<grid, block, 0, stream>>>(A, Bm, sigp, out);
}

// Round 2
// 117.633 us; speedup vs baseline: 1.8113x; 1.8113x over previous
//
#include <hip/hip_runtime.h>

// RBF kernel layer: K[b,n,m] = exp(-max(|a|^2+|b|^2-2ab,0)/(2*sigma^2))
// A: (8,2048,128) f32 -> flat (16384,128); B: (4096,128) f32; out (16384,4096) f32.
// Round 2: precompute bf16 hi/lo split + norms into d_ws (once per launch),
// main kernel stages via plain vector copies with chunk-XOR LDS swizzle
// (conflict-free), 3-pass split MFMA, fused exp epilogue.

typedef __attribute__((ext_vector_type(8))) short bf16x8;
typedef __attribute__((ext_vector_type(4))) float f32x4;

#define NROW_A 16384
#define NROW_B 4096
#define D      128

// ws layout (bytes)
#define OFF_AHI 0u
#define OFF_ALO (OFF_AHI + NROW_A * D * 2u)          //  4,194,304
#define OFF_BHI (OFF_ALO + NROW_A * D * 2u)          //  8,388,608
#define OFF_BLO (OFF_BHI + NROW_B * D * 2u)          //  9,437,184
#define OFF_NA  (OFF_BLO + NROW_B * D * 2u)          // 10,485,760
#define OFF_NB  (OFF_NA + NROW_A * 4u)               // 10,551,296
#define WS_NEED (OFF_NB + NROW_B * 4u)               // 10,567,680

__device__ __forceinline__ short f2bf_hi(float x) {
    union { float f; unsigned u; } v; v.f = x;
    unsigned r = (v.u + 0x7fffu + ((v.u >> 16) & 1u)) >> 16;  // RN-even
    return (short)r;
}
__device__ __forceinline__ float bf2f(short h) {
    union { unsigned u; float f; } v; v.u = ((unsigned)(unsigned short)h) << 16;
    return v.f;
}

// ---------------- precompute: f32 -> bf16 hi/lo + row norms ----------------
__global__ __launch_bounds__(256)
void rbf_precompute(const float* __restrict__ A, const float* __restrict__ Bm,
                    short* __restrict__ Ahi, short* __restrict__ Alo,
                    short* __restrict__ Bhi, short* __restrict__ Blo,
                    float* __restrict__ nA, float* __restrict__ nB) {
    const int g   = blockIdx.x * 256 + threadIdx.x;
    const int row = g >> 4;          // 0..20479
    const int c   = g & 15;          // 16B chunk (8 elems)

    const float* src; short *dhi, *dlo; float* nrm; int r;
    if (row < NROW_A) {
        r = row; src = A + (size_t)r * D;
        dhi = Ahi + (size_t)r * D; dlo = Alo + (size_t)r * D; nrm = nA + r;
    } else {
        r = row - NROW_A; src = Bm + (size_t)r * D;
        dhi = Bhi + (size_t)r * D; dlo = Blo + (size_t)r * D; nrm = nB + r;
    }

    float4 v0 = *(const float4*)(src + c * 8);
    float4 v1 = *(const float4*)(src + c * 8 + 4);
    float f[8] = {v0.x, v0.y, v0.z, v0.w, v1.x, v1.y, v1.z, v1.w};

    bf16x8 hi, lo;
    float ss = 0.0f;
#pragma unroll
    for (int e = 0; e < 8; ++e) {
        short h = f2bf_hi(f[e]);
        hi[e] = h;
        lo[e] = f2bf_hi(f[e] - bf2f(h));
        ss += f[e] * f[e];
    }
    *(bf16x8*)(dhi + c * 8) = hi;
    *(bf16x8*)(dlo + c * 8) = lo;

#pragma unroll
    for (int m = 1; m <= 8; m <<= 1) ss += __shfl_xor(ss, m);
    if (c == 0) *nrm = ss;
}

// ---------------- main: 64x64 tile MFMA GEMM + exp epilogue ----------------
__global__ __launch_bounds__(256, 2)
void rbf_mfma_kernel(const short* __restrict__ Ahi, const short* __restrict__ Alo,
                     const short* __restrict__ Bhi, const short* __restrict__ Blo,
                     const float* __restrict__ nAg, const float* __restrict__ nBg,
                     const float* __restrict__ sigp, float* __restrict__ out) {
    __shared__ __align__(16) short sAhi[64 * 128];
    __shared__ __align__(16) short sAlo[64 * 128];
    __shared__ __align__(16) short sBhi[64 * 128];
    __shared__ __align__(16) short sBlo[64 * 128];
    __shared__ float snA[64];
    __shared__ float snB[64];

    const int tid  = threadIdx.x;
    const int brow = blockIdx.y << 6;
    const int bcol = blockIdx.x << 6;

    // ---- Stage: global bf16 -> LDS with chunk-XOR swizzle (conflict-free) ----
    const int srow = tid >> 2;        // 0..63
    const int sc4  = tid & 3;
#pragma unroll
    for (int it = 0; it < 4; ++it) {
        const int c  = sc4 + (it << 2);          // chunk 0..15
        const int cs = c ^ (srow & 15);          // swizzled chunk
        const size_t gA = (size_t)(brow + srow) * D + c * 8;
        const size_t gB = (size_t)(bcol + srow) * D + c * 8;
        const int l  = srow * 128 + cs * 8;
        *(bf16x8*)&sAhi[l] = *(const bf16x8*)&Ahi[gA];
        *(bf16x8*)&sAlo[l] = *(const bf16x8*)&Alo[gA];
        *(bf16x8*)&sBhi[l] = *(const bf16x8*)&Bhi[gB];
        *(bf16x8*)&sBlo[l] = *(const bf16x8*)&Blo[gB];
    }
    if (tid < 64) snA[tid] = nAg[brow + tid];
    else if (tid < 128) snB[tid - 64] = nBg[bcol + (tid - 64)];
    __syncthreads();

    // ---- Compute: 3-pass split MFMA (hi*hi + hi*lo + lo*hi), K=128 resident ----
    const int lane = tid & 63;
    const int w    = tid >> 6;
    const int wr   = (w >> 1) << 5;     // wave row base: 0 or 32
    const int wc   = (w & 1) << 5;      // wave col base: 0 or 32
    const int lr   = lane & 15;
    const int kb   = lane >> 4;         // k-block 0..3

    f32x4 acc[2][2] = {};

#pragma unroll
    for (int ks = 0; ks < 4; ++ks) {
        const int off = (((ks << 2) + kb) ^ lr) << 3;   // swizzled elem offset
        bf16x8 ahi[2], alo[2], bhi[2], blo[2];
#pragma unroll
        for (int i = 0; i < 2; ++i) {
            const int ar = (wr + (i << 4) + lr) * 128 + off;
            ahi[i] = *(const bf16x8*)(&sAhi[ar]);
            alo[i] = *(const bf16x8*)(&sAlo[ar]);
            const int br = (wc + (i << 4) + lr) * 128 + off;
            bhi[i] = *(const bf16x8*)(&sBhi[br]);
            blo[i] = *(const bf16x8*)(&sBlo[br]);
        }
#pragma unroll
        for (int i = 0; i < 2; ++i) {
#pragma unroll
            for (int j = 0; j < 2; ++j) {
                acc[i][j] = __builtin_amdgcn_mfma_f32_16x16x32_bf16(ahi[i], bhi[j], acc[i][j], 0, 0, 0);
                acc[i][j] = __builtin_amdgcn_mfma_f32_16x16x32_bf16(ahi[i], blo[j], acc[i][j], 0, 0, 0);
                acc[i][j] = __builtin_amdgcn_mfma_f32_16x16x32_bf16(alo[i], bhi[j], acc[i][j], 0, 0, 0);
            }
        }
    }

    // ---- Epilogue: dist2 -> exp, store f32 ----
    float sg = fmaxf(sigp[0], 0.001f);
    const float cc = -0.5f / (sg * sg);

#pragma unroll
    for (int i = 0; i < 2; ++i) {
#pragma unroll
        for (int j = 0; j < 2; ++j) {
#pragma unroll
            for (int r = 0; r < 4; ++r) {
                const int lrow = wr + (i << 4) + (kb << 2) + r;  // D row = (lane>>4)*4+reg
                const int lcol = wc + (j << 4) + lr;             // D col = lane&15
                float d2 = snA[lrow] + snB[lcol] - 2.0f * acc[i][j][r];
                d2 = fmaxf(d2, 0.0f);
                out[(size_t)(brow + lrow) * 4096 + (bcol + lcol)] = __expf(d2 * cc);
            }
        }
    }
}

// ---------------- fallback (round-1 kernel, self-contained) ----------------
#define PK 136
__global__ __launch_bounds__(256, 2)
void rbf_mfma_fallback(const float* __restrict__ A, const float* __restrict__ Bm,
                       const float* __restrict__ sigp, float* __restrict__ out) {
    __shared__ __align__(16) short sAhi[64 * PK];
    __shared__ __align__(16) short sAlo[64 * PK];
    __shared__ __align__(16) short sBhi[64 * PK];
    __shared__ __align__(16) short sBlo[64 * PK];
    __shared__ float nA[64];
    __shared__ float nB[64];

    const int tid  = threadIdx.x;
    const int brow = blockIdx.y << 6;
    const int bcol = blockIdx.x << 6;

    const int r0 = tid >> 5;
    const int kq = (tid & 31) << 2;
#pragma unroll
    for (int it = 0; it < 8; ++it) {
        const int row = r0 + (it << 3);
        const float4 va = *(const float4*)(A  + (size_t)(brow + row) * 128 + kq);
        const float4 vb = *(const float4*)(Bm + (size_t)(bcol + row) * 128 + kq);
        short4 ha, la, hb, lb;
        ha.x = f2bf_hi(va.x); la.x = f2bf_hi(va.x - bf2f(ha.x));
        ha.y = f2bf_hi(va.y); la.y = f2bf_hi(va.y - bf2f(ha.y));
        ha.z = f2bf_hi(va.z); la.z = f2bf_hi(va.z - bf2f(ha.z));
        ha.w = f2bf_hi(va.w); la.w = f2bf_hi(va.w - bf2f(ha.w));
        hb.x = f2bf_hi(vb.x); lb.x = f2bf_hi(vb.x - bf2f(hb.x));
        hb.y = f2bf_hi(vb.y); lb.y = f2bf_hi(vb.y - bf2f(hb.y));
        hb.z = f2bf_hi(vb.z); lb.z = f2bf_hi(vb.z - bf2f(hb.z));
        hb.w = f2bf_hi(vb.w); lb.w = f2bf_hi(vb.w - bf2f(hb.w));
        const int idx = row * PK + kq;
        *(short4*)(&sAhi[idx]) = ha;
        *(short4*)(&sAlo[idx]) = la;
        *(short4*)(&sBhi[idx]) = hb;
        *(short4*)(&sBlo[idx]) = lb;
        float sa = va.x * va.x + va.y * va.y + va.z * va.z + va.w * va.w;
        float sb = vb.x * vb.x + vb.y * vb.y + vb.z * vb.z + vb.w * vb.w;
#pragma unroll
        for (int m = 16; m >= 1; m >>= 1) { sa += __shfl_xor(sa, m); sb += __shfl_xor(sb, m); }
        if ((tid & 31) == 0) { nA[row] = sa; nB[row] = sb; }
    }
    __syncthreads();

    const int lane = tid & 63;
    const int w    = tid >> 6;
    const int wr   = (w >> 1) << 5;
    const int wc   = (w & 1) << 5;
    const int lr   = lane & 15;
    const int kb   = lane >> 4;
    f32x4 acc[2][2] = {};
#pragma unroll
    for (int ks = 0; ks < 4; ++ks) {
        const int kc = (ks << 5) + (kb << 3);
        bf16x8 ahi[2], alo[2], bhi[2], blo[2];
#pragma unroll
        for (int i = 0; i < 2; ++i) {
            const int ar = (wr + (i << 4) + lr) * PK + kc;
            ahi[i] = *(const bf16x8*)(&sAhi[ar]);
            alo[i] = *(const bf16x8*)(&sAlo[ar]);
            const int br = (wc + (i << 4) + lr) * PK + kc;
            bhi[i] = *(const bf16x8*)(&sBhi[br]);
            blo[i] = *(const bf16x8*)(&sBlo[br]);
        }
#pragma unroll
        for (int i = 0; i < 2; ++i)
#pragma unroll
            for (int j = 0; j < 2; ++j) {
                acc[i][j] = __builtin_amdgcn_mfma_f32_16x16x32_bf16(ahi[i], bhi[j], acc[i][j], 0, 0, 0);
                acc[i][j] = __builtin_amdgcn_mfma_f32_16x16x32_bf16(ahi[i], blo[j], acc[i][j], 0, 0, 0);
                acc[i][j] = __builtin_amdgcn_mfma_f32_16x16x32_bf16(alo[i], bhi[j], acc[i][j], 0, 0, 0);
            }
    }
    float sg = fmaxf(sigp[0], 0.001f);
    const float c = -0.5f / (sg * sg);
#pragma unroll
    for (int i = 0; i < 2; ++i)
#pragma unroll
        for (int j = 0; j < 2; ++j)
#pragma unroll
            for (int r = 0; r < 4; ++r) {
                const int lrow = wr + (i << 4) + (kb << 2) + r;
                const int lcol = wc + (j << 4) + lr;
                float d2 = nA[lrow] + nB[lcol] - 2.0f * acc[i][j][r];
                d2 = fmaxf(d2, 0.0f);
                out[(size_t)(brow + lrow) * 4096 + (bcol + lcol)] = __expf(d2 * c);
            }
}

extern "C" void kernel_launch(void* const* d_in, const int* in_sizes, int n_in,
                              void* d_out, int out_size, void* d_ws, size_t ws_size,
                              hipStream_t stream) {
    const float* A    = (const float*)d_in[0];
    const float* Bm   = (const float*)d_in[1];
    const float* sigp = (const float*)d_in[2];
    float* out = (float*)d_out;

    if (ws_size >= WS_NEED) {
        char* ws = (char*)d_ws;
        short* Ahi = (short*)(ws + OFF_AHI);
        short* Alo = (short*)(ws + OFF_ALO);
        short* Bhi = (short*)(ws + OFF_BHI);
        short* Blo = (short*)(ws + OFF_BLO);
        float* nA  = (float*)(ws + OFF_NA);
        float* nB  = (float*)(ws + OFF_NB);

        dim3 pgrid((NROW_A + NROW_B) * 16 / 256, 1, 1);   // 1280 blocks
        rbf_precompute<<<pgrid, 256, 0, stream>>>(A, Bm, Ahi, Alo, Bhi, Blo, nA, nB);

        dim3 grid(4096 / 64, 16384 / 64, 1);
        rbf_mfma_kernel<<<grid, dim3(256, 1, 1), 0, stream>>>(Ahi, Alo, Bhi, Blo, nA, nB, sigp, out);
    } else {
        dim3 grid(4096 / 64, 16384 / 64, 1);
        rbf_mfma_fallback<<<grid, dim3(256, 1, 1), 0, stream>>>(A, Bm, sigp, out);
    }
}

// Round 3
// 106.477 us; speedup vs baseline: 2.0011x; 1.1048x over previous
//
#include <hip/hip_runtime.h>

// RBF kernel layer: K[b,n,m] = exp(-max(|a|^2+|b|^2-2ab,0)/(2*sigma^2))
// A: (8,2048,128) f32 -> flat (16384,128); B: (4096,128) f32; out (16384,4096) f32.
// Round 3: 128x128 tiles (512 thr, 8 waves), XCD-chunked bcol ownership
// (B panels L2-resident), nontemporal output stores, chunk-XOR LDS swizzle,
// precomputed bf16 hi/lo split + norms in d_ws, 3-pass split MFMA.

typedef __attribute__((ext_vector_type(8))) short bf16x8;
typedef __attribute__((ext_vector_type(4))) float f32x4;

#define NROW_A 16384
#define NROW_B 4096
#define D      128

// ws layout (bytes)
#define OFF_AHI 0u
#define OFF_ALO (OFF_AHI + NROW_A * D * 2u)
#define OFF_BHI (OFF_ALO + NROW_A * D * 2u)
#define OFF_BLO (OFF_BHI + NROW_B * D * 2u)
#define OFF_NA  (OFF_BLO + NROW_B * D * 2u)
#define OFF_NB  (OFF_NA + NROW_A * 4u)
#define WS_NEED (OFF_NB + NROW_B * 4u)

__device__ __forceinline__ short f2bf_hi(float x) {
    union { float f; unsigned u; } v; v.f = x;
    unsigned r = (v.u + 0x7fffu + ((v.u >> 16) & 1u)) >> 16;  // RN-even
    return (short)r;
}
__device__ __forceinline__ float bf2f(short h) {
    union { unsigned u; float f; } v; v.u = ((unsigned)(unsigned short)h) << 16;
    return v.f;
}

// ---------------- precompute: f32 -> bf16 hi/lo + row norms ----------------
__global__ __launch_bounds__(256)
void rbf_precompute(const float* __restrict__ A, const float* __restrict__ Bm,
                    short* __restrict__ Ahi, short* __restrict__ Alo,
                    short* __restrict__ Bhi, short* __restrict__ Blo,
                    float* __restrict__ nA, float* __restrict__ nB) {
    const int g   = blockIdx.x * 256 + threadIdx.x;
    const int row = g >> 4;
    const int c   = g & 15;

    const float* src; short *dhi, *dlo; float* nrm; int r;
    if (row < NROW_A) {
        r = row; src = A + (size_t)r * D;
        dhi = Ahi + (size_t)r * D; dlo = Alo + (size_t)r * D; nrm = nA + r;
    } else {
        r = row - NROW_A; src = Bm + (size_t)r * D;
        dhi = Bhi + (size_t)r * D; dlo = Blo + (size_t)r * D; nrm = nB + r;
    }

    float4 v0 = *(const float4*)(src + c * 8);
    float4 v1 = *(const float4*)(src + c * 8 + 4);
    float f[8] = {v0.x, v0.y, v0.z, v0.w, v1.x, v1.y, v1.z, v1.w};

    bf16x8 hi, lo;
    float ss = 0.0f;
#pragma unroll
    for (int e = 0; e < 8; ++e) {
        short h = f2bf_hi(f[e]);
        hi[e] = h;
        lo[e] = f2bf_hi(f[e] - bf2f(h));
        ss += f[e] * f[e];
    }
    *(bf16x8*)(dhi + c * 8) = hi;
    *(bf16x8*)(dlo + c * 8) = lo;

#pragma unroll
    for (int m = 1; m <= 8; m <<= 1) ss += __shfl_xor(ss, m);
    if (c == 0) *nrm = ss;
}

// ---------------- main: 128x128 tile MFMA GEMM + exp epilogue ----------------
__global__ __launch_bounds__(512, 2)
void rbf_mfma_kernel(const short* __restrict__ Ahi, const short* __restrict__ Alo,
                     const short* __restrict__ Bhi, const short* __restrict__ Blo,
                     const float* __restrict__ nAg, const float* __restrict__ nBg,
                     const float* __restrict__ sigp, float* __restrict__ out) {
    __shared__ __align__(16) short sAhi[128 * 128];
    __shared__ __align__(16) short sAlo[128 * 128];
    __shared__ __align__(16) short sBhi[128 * 128];
    __shared__ __align__(16) short sBlo[128 * 128];
    __shared__ float snA[128];
    __shared__ float snB[128];

    const int tid = threadIdx.x;

    // XCD-chunked mapping: XCD k (= lid%8) owns bcol tiles [4k, 4k+4),
    // sweeps brow with bcol as the inner (L2-reuse) loop.
    const int lid  = blockIdx.x;
    const int k    = lid & 7;
    const int s    = lid >> 3;
    const int bcol = ((k << 2) | (s & 3)) << 7;
    const int brow = (s >> 2) << 7;

    // ---- Stage: global bf16 -> LDS, chunk-XOR swizzle (conflict-free) ----
    const int srow = tid >> 2;        // 0..127
    const int sc4  = tid & 3;
#pragma unroll
    for (int it = 0; it < 4; ++it) {
        const int c  = sc4 + (it << 2);          // chunk 0..15
        const int cs = c ^ (srow & 15);          // swizzled chunk
        const size_t gA = (size_t)(brow + srow) * D + c * 8;
        const size_t gB = (size_t)(bcol + srow) * D + c * 8;
        const int l  = srow * 128 + cs * 8;
        *(bf16x8*)&sAhi[l] = *(const bf16x8*)&Ahi[gA];
        *(bf16x8*)&sAlo[l] = *(const bf16x8*)&Alo[gA];
        *(bf16x8*)&sBhi[l] = *(const bf16x8*)&Bhi[gB];
        *(bf16x8*)&sBlo[l] = *(const bf16x8*)&Blo[gB];
    }
    if (tid < 128) snA[tid] = nAg[brow + tid];
    else if (tid < 256) snB[tid - 128] = nBg[bcol + (tid - 128)];
    __syncthreads();

    // ---- Compute: 3-pass split MFMA, K=128 resident, 32x64 per wave ----
    const int lane = tid & 63;
    const int w    = tid >> 6;          // 0..7
    const int wr   = (w >> 1) << 5;     // wave row base: 0/32/64/96
    const int wc   = (w & 1) << 6;      // wave col base: 0/64
    const int lr   = lane & 15;
    const int kb   = lane >> 4;         // k-block 0..3

    f32x4 acc[2][4] = {};

#pragma unroll
    for (int ks = 0; ks < 4; ++ks) {
        const int off = (((ks << 2) + kb) ^ lr) << 3;   // swizzled elem offset
        bf16x8 ahi[2], alo[2], bhi[4], blo[4];
#pragma unroll
        for (int i = 0; i < 2; ++i) {
            const int ar = (wr + (i << 4) + lr) * 128 + off;
            ahi[i] = *(const bf16x8*)(&sAhi[ar]);
            alo[i] = *(const bf16x8*)(&sAlo[ar]);
        }
#pragma unroll
        for (int j = 0; j < 4; ++j) {
            const int br = (wc + (j << 4) + lr) * 128 + off;
            bhi[j] = *(const bf16x8*)(&sBhi[br]);
            blo[j] = *(const bf16x8*)(&sBlo[br]);
        }
#pragma unroll
        for (int i = 0; i < 2; ++i) {
#pragma unroll
            for (int j = 0; j < 4; ++j) {
                acc[i][j] = __builtin_amdgcn_mfma_f32_16x16x32_bf16(ahi[i], bhi[j], acc[i][j], 0, 0, 0);
                acc[i][j] = __builtin_amdgcn_mfma_f32_16x16x32_bf16(ahi[i], blo[j], acc[i][j], 0, 0, 0);
                acc[i][j] = __builtin_amdgcn_mfma_f32_16x16x32_bf16(alo[i], bhi[j], acc[i][j], 0, 0, 0);
            }
        }
    }

    // ---- Epilogue: dist2 -> exp, nontemporal store ----
    float sg = fmaxf(sigp[0], 0.001f);
    const float cc = -0.5f / (sg * sg);

#pragma unroll
    for (int i = 0; i < 2; ++i) {
#pragma unroll
        for (int r = 0; r < 4; ++r) {
            const int lrow = wr + (i << 4) + (kb << 2) + r;  // D row = (lane>>4)*4+reg
            const float na = snA[lrow];
#pragma unroll
            for (int j = 0; j < 4; ++j) {
                const int lcol = wc + (j << 4) + lr;         // D col = lane&15
                float d2 = na + snB[lcol] - 2.0f * acc[i][j][r];
                d2 = fmaxf(d2, 0.0f);
                __builtin_nontemporal_store(__expf(d2 * cc),
                    out + (size_t)(brow + lrow) * 4096 + (bcol + lcol));
            }
        }
    }
}

// ---------------- fallback (self-contained, no ws) ----------------
#define PK 136
__global__ __launch_bounds__(256, 2)
void rbf_mfma_fallback(const float* __restrict__ A, const float* __restrict__ Bm,
                       const float* __restrict__ sigp, float* __restrict__ out) {
    __shared__ __align__(16) short sAhi[64 * PK];
    __shared__ __align__(16) short sAlo[64 * PK];
    __shared__ __align__(16) short sBhi[64 * PK];
    __shared__ __align__(16) short sBlo[64 * PK];
    __shared__ float nA[64];
    __shared__ float nB[64];

    const int tid  = threadIdx.x;
    const int brow = blockIdx.y << 6;
    const int bcol = blockIdx.x << 6;

    const int r0 = tid >> 5;
    const int kq = (tid & 31) << 2;
#pragma unroll
    for (int it = 0; it < 8; ++it) {
        const int row = r0 + (it << 3);
        const float4 va = *(const float4*)(A  + (size_t)(brow + row) * 128 + kq);
        const float4 vb = *(const float4*)(Bm + (size_t)(bcol + row) * 128 + kq);
        short4 ha, la, hb, lb;
        ha.x = f2bf_hi(va.x); la.x = f2bf_hi(va.x - bf2f(ha.x));
        ha.y = f2bf_hi(va.y); la.y = f2bf_hi(va.y - bf2f(ha.y));
        ha.z = f2bf_hi(va.z); la.z = f2bf_hi(va.z - bf2f(ha.z));
        ha.w = f2bf_hi(va.w); la.w = f2bf_hi(va.w - bf2f(ha.w));
        hb.x = f2bf_hi(vb.x); lb.x = f2bf_hi(vb.x - bf2f(hb.x));
        hb.y = f2bf_hi(vb.y); lb.y = f2bf_hi(vb.y - bf2f(hb.y));
        hb.z = f2bf_hi(vb.z); lb.z = f2bf_hi(vb.z - bf2f(hb.z));
        hb.w = f2bf_hi(vb.w); lb.w = f2bf_hi(vb.w - bf2f(hb.w));
        const int idx = row * PK + kq;
        *(short4*)(&sAhi[idx]) = ha;
        *(short4*)(&sAlo[idx]) = la;
        *(short4*)(&sBhi[idx]) = hb;
        *(short4*)(&sBlo[idx]) = lb;
        float sa = va.x * va.x + va.y * va.y + va.z * va.z + va.w * va.w;
        float sb = vb.x * vb.x + vb.y * vb.y + vb.z * vb.z + vb.w * vb.w;
#pragma unroll
        for (int m = 16; m >= 1; m >>= 1) { sa += __shfl_xor(sa, m); sb += __shfl_xor(sb, m); }
        if ((tid & 31) == 0) { nA[row] = sa; nB[row] = sb; }
    }
    __syncthreads();

    const int lane = tid & 63;
    const int w    = tid >> 6;
    const int wr   = (w >> 1) << 5;
    const int wc   = (w & 1) << 5;
    const int lr   = lane & 15;
    const int kb   = lane >> 4;
    f32x4 acc[2][2] = {};
#pragma unroll
    for (int ks = 0; ks < 4; ++ks) {
        const int kc = (ks << 5) + (kb << 3);
        bf16x8 ahi[2], alo[2], bhi[2], blo[2];
#pragma unroll
        for (int i = 0; i < 2; ++i) {
            const int ar = (wr + (i << 4) + lr) * PK + kc;
            ahi[i] = *(const bf16x8*)(&sAhi[ar]);
            alo[i] = *(const bf16x8*)(&sAlo[ar]);
            const int br = (wc + (i << 4) + lr) * PK + kc;
            bhi[i] = *(const bf16x8*)(&sBhi[br]);
            blo[i] = *(const bf16x8*)(&sBlo[br]);
        }
#pragma unroll
        for (int i = 0; i < 2; ++i)
#pragma unroll
            for (int j = 0; j < 2; ++j) {
                acc[i][j] = __builtin_amdgcn_mfma_f32_16x16x32_bf16(ahi[i], bhi[j], acc[i][j], 0, 0, 0);
                acc[i][j] = __builtin_amdgcn_mfma_f32_16x16x32_bf16(ahi[i], blo[j], acc[i][j], 0, 0, 0);
                acc[i][j] = __builtin_amdgcn_mfma_f32_16x16x32_bf16(alo[i], bhi[j], acc[i][j], 0, 0, 0);
            }
    }
    float sg = fmaxf(sigp[0], 0.001f);
    const float c = -0.5f / (sg * sg);
#pragma unroll
    for (int i = 0; i < 2; ++i)
#pragma unroll
        for (int j = 0; j < 2; ++j)
#pragma unroll
            for (int r = 0; r < 4; ++r) {
                const int lrow = wr + (i << 4) + (kb << 2) + r;
                const int lcol = wc + (j << 4) + lr;
                float d2 = nA[lrow] + nB[lcol] - 2.0f * acc[i][j][r];
                d2 = fmaxf(d2, 0.0f);
                out[(size_t)(brow + lrow) * 4096 + (bcol + lcol)] = __expf(d2 * c);
            }
}

extern "C" void kernel_launch(void* const* d_in, const int* in_sizes, int n_in,
                              void* d_out, int out_size, void* d_ws, size_t ws_size,
                              hipStream_t stream) {
    const float* A    = (const float*)d_in[0];
    const float* Bm   = (const float*)d_in[1];
    const float* sigp = (const float*)d_in[2];
    float* out = (float*)d_out;

    if (ws_size >= WS_NEED) {
        char* ws = (char*)d_ws;
        short* Ahi = (short*)(ws + OFF_AHI);
        short* Alo = (short*)(ws + OFF_ALO);
        short* Bhi = (short*)(ws + OFF_BHI);
        short* Blo = (short*)(ws + OFF_BLO);
        float* nA  = (float*)(ws + OFF_NA);
        float* nB  = (float*)(ws + OFF_NB);

        dim3 pgrid((NROW_A + NROW_B) * 16 / 256, 1, 1);
        rbf_precompute<<<pgrid, 256, 0, stream>>>(A, Bm, Ahi, Alo, Bhi, Blo, nA, nB);

        // 4096 blocks: (16384/128) x (4096/128), XCD-chunked inside kernel
        rbf_mfma_kernel<<<dim3(4096, 1, 1), dim3(512, 1, 1), 0, stream>>>(
            Ahi, Alo, Bhi, Blo, nA, nB, sigp, out);
    } else {
        dim3 grid(4096 / 64, 16384 / 64, 1);
        rbf_mfma_fallback<<<grid, dim3(256, 1, 1), 0, stream>>>(A, Bm, sigp, out);
    }
}

// Round 4
// 96.492 us; speedup vs baseline: 2.2081x; 1.1035x over previous
//
#include <hip/hip_runtime.h>

// RBF kernel layer: K[b,n,m] = exp(-max(|a|^2+|b|^2-2ab,0)/(2*sigma^2))
// A: (8,2048,128) f32 -> flat (16384,128); B: (4096,128) f32; out (16384,4096) f32.
// Round 4: persistent-ish blocks (B staged once, 8 brow tiles per block),
// T14 async A staging (issue-early/write-late), operand-swapped MFMA so each
// lane owns 4 consecutive out columns -> float4 NT stores. 3-pass bf16 split.

typedef __attribute__((ext_vector_type(8))) short bf16x8;
typedef __attribute__((ext_vector_type(4))) float f32x4;

#define NROW_A 16384
#define NROW_B 4096
#define D      128

// ws layout (bytes)
#define OFF_AHI 0u
#define OFF_ALO (OFF_AHI + NROW_A * D * 2u)
#define OFF_BHI (OFF_ALO + NROW_A * D * 2u)
#define OFF_BLO (OFF_BHI + NROW_B * D * 2u)
#define OFF_NA  (OFF_BLO + NROW_B * D * 2u)
#define OFF_NB  (OFF_NA + NROW_A * 4u)
#define WS_NEED (OFF_NB + NROW_B * 4u)

__device__ __forceinline__ short f2bf_hi(float x) {
    union { float f; unsigned u; } v; v.f = x;
    unsigned r = (v.u + 0x7fffu + ((v.u >> 16) & 1u)) >> 16;  // RN-even
    return (short)r;
}
__device__ __forceinline__ float bf2f(short h) {
    union { unsigned u; float f; } v; v.u = ((unsigned)(unsigned short)h) << 16;
    return v.f;
}

// ---------------- precompute: f32 -> bf16 hi/lo + row norms ----------------
__global__ __launch_bounds__(256)
void rbf_precompute(const float* __restrict__ A, const float* __restrict__ Bm,
                    short* __restrict__ Ahi, short* __restrict__ Alo,
                    short* __restrict__ Bhi, short* __restrict__ Blo,
                    float* __restrict__ nA, float* __restrict__ nB) {
    const int g   = blockIdx.x * 256 + threadIdx.x;
    const int row = g >> 4;
    const int c   = g & 15;

    const float* src; short *dhi, *dlo; float* nrm; int r;
    if (row < NROW_A) {
        r = row; src = A + (size_t)r * D;
        dhi = Ahi + (size_t)r * D; dlo = Alo + (size_t)r * D; nrm = nA + r;
    } else {
        r = row - NROW_A; src = Bm + (size_t)r * D;
        dhi = Bhi + (size_t)r * D; dlo = Blo + (size_t)r * D; nrm = nB + r;
    }

    float4 v0 = *(const float4*)(src + c * 8);
    float4 v1 = *(const float4*)(src + c * 8 + 4);
    float f[8] = {v0.x, v0.y, v0.z, v0.w, v1.x, v1.y, v1.z, v1.w};

    bf16x8 hi, lo;
    float ss = 0.0f;
#pragma unroll
    for (int e = 0; e < 8; ++e) {
        short h = f2bf_hi(f[e]);
        hi[e] = h;
        lo[e] = f2bf_hi(f[e] - bf2f(h));
        ss += f[e] * f[e];
    }
    *(bf16x8*)(dhi + c * 8) = hi;
    *(bf16x8*)(dlo + c * 8) = lo;

#pragma unroll
    for (int m = 1; m <= 8; m <<= 1) ss += __shfl_xor(ss, m);
    if (c == 0) *nrm = ss;
}

// ---------------- main: persistent 128x128 tiles, B resident ----------------
__global__ __launch_bounds__(512, 2)
void rbf_mfma_persist(const short* __restrict__ Ahi, const short* __restrict__ Alo,
                      const short* __restrict__ Bhi, const short* __restrict__ Blo,
                      const float* __restrict__ nAg, const float* __restrict__ nBg,
                      const float* __restrict__ sigp, float* __restrict__ out) {
    __shared__ __align__(16) short sA[2][128 * 128];   // [hi/lo][row*128 + swz]
    __shared__ __align__(16) short sB[2][128 * 128];
    __shared__ __align__(16) float snA[128];
    __shared__ __align__(16) float snB[128];

    const int tid = threadIdx.x;
    const int bid = blockIdx.x;
    // XCD-chunked: xcd = bid&7 owns 4 bcol tiles; 16 brow-groups of 8 tiles.
    const int xcd = bid & 7;
    const int idx = bid >> 3;                 // 0..63
    const int bcol = ((xcd << 2) + (idx & 3)) << 7;
    const int bg   = idx >> 2;                // 0..15

    const int srow = tid >> 2;                // 0..127
    const int sc4  = tid & 3;

    // ---- prologue: stage B panel (hi+lo) + snB; stage A(0) + snA ----
#pragma unroll
    for (int it = 0; it < 4; ++it) {
        const int c  = sc4 + (it << 2);
        const int cs = c ^ (srow & 15);
        const int l  = srow * 128 + cs * 8;
        *(bf16x8*)&sB[0][l] = *(const bf16x8*)&Bhi[(size_t)(bcol + srow) * D + c * 8];
        *(bf16x8*)&sB[1][l] = *(const bf16x8*)&Blo[(size_t)(bcol + srow) * D + c * 8];
    }
    if (tid < 128) snB[tid] = nBg[bcol + tid];

    {
        const int brow0 = (bg << 3) << 7;
#pragma unroll
        for (int it = 0; it < 4; ++it) {
            const int c  = sc4 + (it << 2);
            const int cs = c ^ (srow & 15);
            const int l  = srow * 128 + cs * 8;
            *(bf16x8*)&sA[0][l] = *(const bf16x8*)&Ahi[(size_t)(brow0 + srow) * D + c * 8];
            *(bf16x8*)&sA[1][l] = *(const bf16x8*)&Alo[(size_t)(brow0 + srow) * D + c * 8];
        }
        if (tid >= 384) snA[tid - 384] = nAg[brow0 + tid - 384];
    }
    __syncthreads();

    const int lane = tid & 63;
    const int w    = tid >> 6;            // 0..7
    const int wr   = (w >> 1) << 5;       // 0/32/64/96
    const int wc   = (w & 1) << 6;        // 0/64
    const int lr   = lane & 15;
    const int kb   = lane >> 4;           // 0..3

    float sg = fmaxf(sigp[0], 0.001f);
    const float cc = -0.5f / (sg * sg);

    bf16x8 rh[4], rl[4];
    float rn = 0.0f;

    for (int t = 0; t < 8; ++t) {
        const int browt = ((bg << 3) + t) << 7;

        // ---- issue A(t+1) global loads early (T14: in flight under compute) ----
        if (t < 7) {
            const int brn = browt + 128;
#pragma unroll
            for (int it = 0; it < 4; ++it) {
                const int c = sc4 + (it << 2);
                rh[it] = *(const bf16x8*)&Ahi[(size_t)(brn + srow) * D + c * 8];
                rl[it] = *(const bf16x8*)&Alo[(size_t)(brn + srow) * D + c * 8];
            }
            if (tid >= 384) rn = nAg[brn + tid - 384];
        }

        // ---- compute: 3-pass split MFMA, operand-swapped ----
        f32x4 acc[2][4] = {};
#pragma unroll
        for (int ks = 0; ks < 4; ++ks) {
            const int off = (((ks << 2) + kb) ^ lr) << 3;
            bf16x8 afh[2], afl[2], bfh[4], bfl[4];
#pragma unroll
            for (int i = 0; i < 2; ++i) {
                const int ar = (wr + (i << 4) + lr) * 128 + off;
                afh[i] = *(const bf16x8*)&sA[0][ar];
                afl[i] = *(const bf16x8*)&sA[1][ar];
            }
#pragma unroll
            for (int j = 0; j < 4; ++j) {
                const int br = (wc + (j << 4) + lr) * 128 + off;
                bfh[j] = *(const bf16x8*)&sB[0][br];
                bfl[j] = *(const bf16x8*)&sB[1][br];
            }
#pragma unroll
            for (int i = 0; i < 2; ++i) {
#pragma unroll
                for (int j = 0; j < 4; ++j) {
                    // swapped: first operand = B fragment -> D "row" dim = out COLS
                    acc[i][j] = __builtin_amdgcn_mfma_f32_16x16x32_bf16(bfh[j], afh[i], acc[i][j], 0, 0, 0);
                    acc[i][j] = __builtin_amdgcn_mfma_f32_16x16x32_bf16(bfl[j], afh[i], acc[i][j], 0, 0, 0);
                    acc[i][j] = __builtin_amdgcn_mfma_f32_16x16x32_bf16(bfh[j], afl[i], acc[i][j], 0, 0, 0);
                }
            }
        }

        // ---- epilogue: lane owns 4 consecutive out cols -> float4 NT store ----
#pragma unroll
        for (int i = 0; i < 2; ++i) {
            const int orow = wr + (i << 4) + lr;      // out row = lane&15 dim
            const float na = snA[orow];
#pragma unroll
            for (int j = 0; j < 4; ++j) {
                const int ocol = wc + (j << 4) + (kb << 2);   // 4 consecutive cols
                const f32x4 nb = *(const f32x4*)&snB[ocol];
                f32x4 v;
#pragma unroll
                for (int r = 0; r < 4; ++r) {
                    float d2 = fmaxf(na + nb[r] - 2.0f * acc[i][j][r], 0.0f);
                    v[r] = __expf(d2 * cc);
                }
                __builtin_nontemporal_store(v,
                    (f32x4*)(out + (size_t)(browt + orow) * 4096 + bcol + ocol));
            }
        }

        __syncthreads();   // all waves done reading sA(t)/snA(t)

        if (t < 7) {
            // write-late: waitcnt here only drains the (older) loads, not stores
#pragma unroll
            for (int it = 0; it < 4; ++it) {
                const int c  = sc4 + (it << 2);
                const int cs = c ^ (srow & 15);
                const int l  = srow * 128 + cs * 8;
                *(bf16x8*)&sA[0][l] = rh[it];
                *(bf16x8*)&sA[1][l] = rl[it];
            }
            if (tid >= 384) snA[tid - 384] = rn;
            __syncthreads();
        }
    }
}

// ---------------- fallback (self-contained, no ws) ----------------
#define PK 136
__global__ __launch_bounds__(256, 2)
void rbf_mfma_fallback(const float* __restrict__ A, const float* __restrict__ Bm,
                       const float* __restrict__ sigp, float* __restrict__ out) {
    __shared__ __align__(16) short sAhi[64 * PK];
    __shared__ __align__(16) short sAlo[64 * PK];
    __shared__ __align__(16) short sBhi[64 * PK];
    __shared__ __align__(16) short sBlo[64 * PK];
    __shared__ float nA[64];
    __shared__ float nB[64];

    const int tid  = threadIdx.x;
    const int brow = blockIdx.y << 6;
    const int bcol = blockIdx.x << 6;

    const int r0 = tid >> 5;
    const int kq = (tid & 31) << 2;
#pragma unroll
    for (int it = 0; it < 8; ++it) {
        const int row = r0 + (it << 3);
        const float4 va = *(const float4*)(A  + (size_t)(brow + row) * 128 + kq);
        const float4 vb = *(const float4*)(Bm + (size_t)(bcol + row) * 128 + kq);
        short4 ha, la, hb, lb;
        ha.x = f2bf_hi(va.x); la.x = f2bf_hi(va.x - bf2f(ha.x));
        ha.y = f2bf_hi(va.y); la.y = f2bf_hi(va.y - bf2f(ha.y));
        ha.z = f2bf_hi(va.z); la.z = f2bf_hi(va.z - bf2f(ha.z));
        ha.w = f2bf_hi(va.w); la.w = f2bf_hi(va.w - bf2f(ha.w));
        hb.x = f2bf_hi(vb.x); lb.x = f2bf_hi(vb.x - bf2f(hb.x));
        hb.y = f2bf_hi(vb.y); lb.y = f2bf_hi(vb.y - bf2f(hb.y));
        hb.z = f2bf_hi(vb.z); lb.z = f2bf_hi(vb.z - bf2f(hb.z));
        hb.w = f2bf_hi(vb.w); lb.w = f2bf_hi(vb.w - bf2f(hb.w));
        const int idx = row * PK + kq;
        *(short4*)(&sAhi[idx]) = ha;
        *(short4*)(&sAlo[idx]) = la;
        *(short4*)(&sBhi[idx]) = hb;
        *(short4*)(&sBlo[idx]) = lb;
        float sa = va.x * va.x + va.y * va.y + va.z * va.z + va.w * va.w;
        float sb = vb.x * vb.x + vb.y * vb.y + vb.z * vb.z + vb.w * vb.w;
#pragma unroll
        for (int m = 16; m >= 1; m >>= 1) { sa += __shfl_xor(sa, m); sb += __shfl_xor(sb, m); }
        if ((tid & 31) == 0) { nA[row] = sa; nB[row] = sb; }
    }
    __syncthreads();

    const int lane = tid & 63;
    const int w    = tid >> 6;
    const int wr   = (w >> 1) << 5;
    const int wc   = (w & 1) << 5;
    const int lr   = lane & 15;
    const int kb   = lane >> 4;
    f32x4 acc[2][2] = {};
#pragma unroll
    for (int ks = 0; ks < 4; ++ks) {
        const int kc = (ks << 5) + (kb << 3);
        bf16x8 ahi[2], alo[2], bhi[2], blo[2];
#pragma unroll
        for (int i = 0; i < 2; ++i) {
            const int ar = (wr + (i << 4) + lr) * PK + kc;
            ahi[i] = *(const bf16x8*)(&sAhi[ar]);
            alo[i] = *(const bf16x8*)(&sAlo[ar]);
            const int br = (wc + (i << 4) + lr) * PK + kc;
            bhi[i] = *(const bf16x8*)(&sBhi[br]);
            blo[i] = *(const bf16x8*)(&sBlo[br]);
        }
#pragma unroll
        for (int i = 0; i < 2; ++i)
#pragma unroll
            for (int j = 0; j < 2; ++j) {
                acc[i][j] = __builtin_amdgcn_mfma_f32_16x16x32_bf16(ahi[i], bhi[j], acc[i][j], 0, 0, 0);
                acc[i][j] = __builtin_amdgcn_mfma_f32_16x16x32_bf16(ahi[i], blo[j], acc[i][j], 0, 0, 0);
                acc[i][j] = __builtin_amdgcn_mfma_f32_16x16x32_bf16(alo[i], bhi[j], acc[i][j], 0, 0, 0);
            }
    }
    float sg = fmaxf(sigp[0], 0.001f);
    const float c = -0.5f / (sg * sg);
#pragma unroll
    for (int i = 0; i < 2; ++i)
#pragma unroll
        for (int j = 0; j < 2; ++j)
#pragma unroll
            for (int r = 0; r < 4; ++r) {
                const int lrow = wr + (i << 4) + (kb << 2) + r;
                const int lcol = wc + (j << 4) + lr;
                float d2 = nA[lrow] + nB[lcol] - 2.0f * acc[i][j][r];
                d2 = fmaxf(d2, 0.0f);
                out[(size_t)(brow + lrow) * 4096 + (bcol + lcol)] = __expf(d2 * c);
            }
}

extern "C" void kernel_launch(void* const* d_in, const int* in_sizes, int n_in,
                              void* d_out, int out_size, void* d_ws, size_t ws_size,
                              hipStream_t stream) {
    const float* A    = (const float*)d_in[0];
    const float* Bm   = (const float*)d_in[1];
    const float* sigp = (const float*)d_in[2];
    float* out = (float*)d_out;

    if (ws_size >= WS_NEED) {
        char* ws = (char*)d_ws;
        short* Ahi = (short*)(ws + OFF_AHI);
        short* Alo = (short*)(ws + OFF_ALO);
        short* Bhi = (short*)(ws + OFF_BHI);
        short* Blo = (short*)(ws + OFF_BLO);
        float* nA  = (float*)(ws + OFF_NA);
        float* nB  = (float*)(ws + OFF_NB);

        dim3 pgrid((NROW_A + NROW_B) * 16 / 256, 1, 1);
        rbf_precompute<<<pgrid, 256, 0, stream>>>(A, Bm, Ahi, Alo, Bhi, Blo, nA, nB);

        // 512 persistent-ish blocks: 32 bcol tiles x 16 brow-groups (8 tiles each)
        rbf_mfma_persist<<<dim3(512, 1, 1), dim3(512, 1, 1), 0, stream>>>(
            Ahi, Alo, Bhi, Blo, nA, nB, sigp, out);
    } else {
        dim3 grid(4096 / 64, 16384 / 64, 1);
        rbf_mfma_fallback<<<grid, dim3(256, 1, 1), 0, stream>>>(A, Bm, sigp, out);
    }
}

// Round 5
// 79.818 us; speedup vs baseline: 2.6694x; 1.2089x over previous
//
#include <hip/hip_runtime.h>

// RBF kernel layer: K[b,n,m] = exp(-max(|a|^2+|b|^2-2ab,0)/(2*sigma^2))
// A: (8,2048,128) f32 -> flat (16384,128); B: (4096,128) f32; out (16384,4096) f32.
// Round 5: same as round 4 but PLAIN stores through L2 (NT stores were pushing
// 64B transactions to HBM without merge -> ~3.3 TB/s write path; fill kernel
// proves plain path does 85% peak). Persistent blocks, B staged once, T14
// async A staging, operand-swapped MFMA -> float4 stores, 3-pass bf16 split.

typedef __attribute__((ext_vector_type(8))) short bf16x8;
typedef __attribute__((ext_vector_type(4))) float f32x4;

#define NROW_A 16384
#define NROW_B 4096
#define D      128

// ws layout (bytes)
#define OFF_AHI 0u
#define OFF_ALO (OFF_AHI + NROW_A * D * 2u)
#define OFF_BHI (OFF_ALO + NROW_A * D * 2u)
#define OFF_BLO (OFF_BHI + NROW_B * D * 2u)
#define OFF_NA  (OFF_BLO + NROW_B * D * 2u)
#define OFF_NB  (OFF_NA + NROW_A * 4u)
#define WS_NEED (OFF_NB + NROW_B * 4u)

__device__ __forceinline__ short f2bf_hi(float x) {
    union { float f; unsigned u; } v; v.f = x;
    unsigned r = (v.u + 0x7fffu + ((v.u >> 16) & 1u)) >> 16;  // RN-even
    return (short)r;
}
__device__ __forceinline__ float bf2f(short h) {
    union { unsigned u; float f; } v; v.u = ((unsigned)(unsigned short)h) << 16;
    return v.f;
}

// ---------------- precompute: f32 -> bf16 hi/lo + row norms ----------------
__global__ __launch_bounds__(256)
void rbf_precompute(const float* __restrict__ A, const float* __restrict__ Bm,
                    short* __restrict__ Ahi, short* __restrict__ Alo,
                    short* __restrict__ Bhi, short* __restrict__ Blo,
                    float* __restrict__ nA, float* __restrict__ nB) {
    const int g   = blockIdx.x * 256 + threadIdx.x;
    const int row = g >> 4;
    const int c   = g & 15;

    const float* src; short *dhi, *dlo; float* nrm; int r;
    if (row < NROW_A) {
        r = row; src = A + (size_t)r * D;
        dhi = Ahi + (size_t)r * D; dlo = Alo + (size_t)r * D; nrm = nA + r;
    } else {
        r = row - NROW_A; src = Bm + (size_t)r * D;
        dhi = Bhi + (size_t)r * D; dlo = Blo + (size_t)r * D; nrm = nB + r;
    }

    float4 v0 = *(const float4*)(src + c * 8);
    float4 v1 = *(const float4*)(src + c * 8 + 4);
    float f[8] = {v0.x, v0.y, v0.z, v0.w, v1.x, v1.y, v1.z, v1.w};

    bf16x8 hi, lo;
    float ss = 0.0f;
#pragma unroll
    for (int e = 0; e < 8; ++e) {
        short h = f2bf_hi(f[e]);
        hi[e] = h;
        lo[e] = f2bf_hi(f[e] - bf2f(h));
        ss += f[e] * f[e];
    }
    *(bf16x8*)(dhi + c * 8) = hi;
    *(bf16x8*)(dlo + c * 8) = lo;

#pragma unroll
    for (int m = 1; m <= 8; m <<= 1) ss += __shfl_xor(ss, m);
    if (c == 0) *nrm = ss;
}

// ---------------- main: persistent 128x128 tiles, B resident ----------------
__global__ __launch_bounds__(512, 1)
void rbf_mfma_persist(const short* __restrict__ Ahi, const short* __restrict__ Alo,
                      const short* __restrict__ Bhi, const short* __restrict__ Blo,
                      const float* __restrict__ nAg, const float* __restrict__ nBg,
                      const float* __restrict__ sigp, float* __restrict__ out) {
    __shared__ __align__(16) short sA[2][128 * 128];   // [hi/lo][row*128 + swz]
    __shared__ __align__(16) short sB[2][128 * 128];
    __shared__ __align__(16) float snA[128];
    __shared__ __align__(16) float snB[128];

    const int tid = threadIdx.x;
    const int bid = blockIdx.x;
    // XCD-chunked: xcd = bid&7 owns 4 bcol tiles; 16 brow-groups of 8 tiles.
    const int xcd = bid & 7;
    const int idx = bid >> 3;                 // 0..63
    const int bcol = ((xcd << 2) + (idx & 3)) << 7;
    const int bg   = idx >> 2;                // 0..15

    const int srow = tid >> 2;                // 0..127
    const int sc4  = tid & 3;

    // ---- prologue: stage B panel (hi+lo) + snB; stage A(0) + snA ----
#pragma unroll
    for (int it = 0; it < 4; ++it) {
        const int c  = sc4 + (it << 2);
        const int cs = c ^ (srow & 15);
        const int l  = srow * 128 + cs * 8;
        *(bf16x8*)&sB[0][l] = *(const bf16x8*)&Bhi[(size_t)(bcol + srow) * D + c * 8];
        *(bf16x8*)&sB[1][l] = *(const bf16x8*)&Blo[(size_t)(bcol + srow) * D + c * 8];
    }
    if (tid < 128) snB[tid] = nBg[bcol + tid];

    {
        const int brow0 = (bg << 3) << 7;
#pragma unroll
        for (int it = 0; it < 4; ++it) {
            const int c  = sc4 + (it << 2);
            const int cs = c ^ (srow & 15);
            const int l  = srow * 128 + cs * 8;
            *(bf16x8*)&sA[0][l] = *(const bf16x8*)&Ahi[(size_t)(brow0 + srow) * D + c * 8];
            *(bf16x8*)&sA[1][l] = *(const bf16x8*)&Alo[(size_t)(brow0 + srow) * D + c * 8];
        }
        if (tid >= 384) snA[tid - 384] = nAg[brow0 + tid - 384];
    }
    __syncthreads();

    const int lane = tid & 63;
    const int w    = tid >> 6;            // 0..7
    const int wr   = (w >> 1) << 5;       // 0/32/64/96
    const int wc   = (w & 1) << 6;        // 0/64
    const int lr   = lane & 15;
    const int kb   = lane >> 4;           // 0..3

    float sg = fmaxf(sigp[0], 0.001f);
    const float cc = -0.5f / (sg * sg);

    bf16x8 rh[4], rl[4];
    float rn = 0.0f;

    for (int t = 0; t < 8; ++t) {
        const int browt = ((bg << 3) + t) << 7;

        // ---- issue A(t+1) global loads early (T14: in flight under compute) ----
        if (t < 7) {
            const int brn = browt + 128;
#pragma unroll
            for (int it = 0; it < 4; ++it) {
                const int c = sc4 + (it << 2);
                rh[it] = *(const bf16x8*)&Ahi[(size_t)(brn + srow) * D + c * 8];
                rl[it] = *(const bf16x8*)&Alo[(size_t)(brn + srow) * D + c * 8];
            }
            if (tid >= 384) rn = nAg[brn + tid - 384];
        }

        // ---- compute: 3-pass split MFMA, operand-swapped ----
        f32x4 acc[2][4] = {};
#pragma unroll
        for (int ks = 0; ks < 4; ++ks) {
            const int off = (((ks << 2) + kb) ^ lr) << 3;
            bf16x8 afh[2], afl[2], bfh[4], bfl[4];
#pragma unroll
            for (int i = 0; i < 2; ++i) {
                const int ar = (wr + (i << 4) + lr) * 128 + off;
                afh[i] = *(const bf16x8*)&sA[0][ar];
                afl[i] = *(const bf16x8*)&sA[1][ar];
            }
#pragma unroll
            for (int j = 0; j < 4; ++j) {
                const int br = (wc + (j << 4) + lr) * 128 + off;
                bfh[j] = *(const bf16x8*)&sB[0][br];
                bfl[j] = *(const bf16x8*)&sB[1][br];
            }
#pragma unroll
            for (int i = 0; i < 2; ++i) {
#pragma unroll
                for (int j = 0; j < 4; ++j) {
                    // swapped: first operand = B fragment -> D "row" dim = out COLS
                    acc[i][j] = __builtin_amdgcn_mfma_f32_16x16x32_bf16(bfh[j], afh[i], acc[i][j], 0, 0, 0);
                    acc[i][j] = __builtin_amdgcn_mfma_f32_16x16x32_bf16(bfl[j], afh[i], acc[i][j], 0, 0, 0);
                    acc[i][j] = __builtin_amdgcn_mfma_f32_16x16x32_bf16(bfh[j], afl[i], acc[i][j], 0, 0, 0);
                }
            }
        }

        // ---- epilogue: lane owns 4 consecutive out cols -> float4 store (L2) ----
#pragma unroll
        for (int i = 0; i < 2; ++i) {
            const int orow = wr + (i << 4) + lr;      // out row = lane&15 dim
            const float na = snA[orow];
#pragma unroll
            for (int j = 0; j < 4; ++j) {
                const int ocol = wc + (j << 4) + (kb << 2);   // 4 consecutive cols
                const f32x4 nb = *(const f32x4*)&snB[ocol];
                f32x4 v;
#pragma unroll
                for (int r = 0; r < 4; ++r) {
                    float d2 = fmaxf(na + nb[r] - 2.0f * acc[i][j][r], 0.0f);
                    v[r] = __expf(d2 * cc);
                }
                *(f32x4*)(out + (size_t)(browt + orow) * 4096 + bcol + ocol) = v;
            }
        }

        __syncthreads();   // all waves done reading sA(t)/snA(t)

        if (t < 7) {
            // write-late: waitcnt here only drains the (older) loads, not stores
#pragma unroll
            for (int it = 0; it < 4; ++it) {
                const int c  = sc4 + (it << 2);
                const int cs = c ^ (srow & 15);
                const int l  = srow * 128 + cs * 8;
                *(bf16x8*)&sA[0][l] = rh[it];
                *(bf16x8*)&sA[1][l] = rl[it];
            }
            if (tid >= 384) snA[tid - 384] = rn;
            __syncthreads();
        }
    }
}

// ---------------- fallback (self-contained, no ws) ----------------
#define PK 136
__global__ __launch_bounds__(256, 2)
void rbf_mfma_fallback(const float* __restrict__ A, const float* __restrict__ Bm,
                       const float* __restrict__ sigp, float* __restrict__ out) {
    __shared__ __align__(16) short sAhi[64 * PK];
    __shared__ __align__(16) short sAlo[64 * PK];
    __shared__ __align__(16) short sBhi[64 * PK];
    __shared__ __align__(16) short sBlo[64 * PK];
    __shared__ float nA[64];
    __shared__ float nB[64];

    const int tid  = threadIdx.x;
    const int brow = blockIdx.y << 6;
    const int bcol = blockIdx.x << 6;

    const int r0 = tid >> 5;
    const int kq = (tid & 31) << 2;
#pragma unroll
    for (int it = 0; it < 8; ++it) {
        const int row = r0 + (it << 3);
        const float4 va = *(const float4*)(A  + (size_t)(brow + row) * 128 + kq);
        const float4 vb = *(const float4*)(Bm + (size_t)(bcol + row) * 128 + kq);
        short4 ha, la, hb, lb;
        ha.x = f2bf_hi(va.x); la.x = f2bf_hi(va.x - bf2f(ha.x));
        ha.y = f2bf_hi(va.y); la.y = f2bf_hi(va.y - bf2f(ha.y));
        ha.z = f2bf_hi(va.z); la.z = f2bf_hi(va.z - bf2f(ha.z));
        ha.w = f2bf_hi(va.w); la.w = f2bf_hi(va.w - bf2f(ha.w));
        hb.x = f2bf_hi(vb.x); lb.x = f2bf_hi(vb.x - bf2f(hb.x));
        hb.y = f2bf_hi(vb.y); lb.y = f2bf_hi(vb.y - bf2f(hb.y));
        hb.z = f2bf_hi(vb.z); lb.z = f2bf_hi(vb.z - bf2f(hb.z));
        hb.w = f2bf_hi(vb.w); lb.w = f2bf_hi(vb.w - bf2f(hb.w));
        const int idx = row * PK + kq;
        *(short4*)(&sAhi[idx]) = ha;
        *(short4*)(&sAlo[idx]) = la;
        *(short4*)(&sBhi[idx]) = hb;
        *(short4*)(&sBlo[idx]) = lb;
        float sa = va.x * va.x + va.y * va.y + va.z * va.z + va.w * va.w;
        float sb = vb.x * vb.x + vb.y * vb.y + vb.z * vb.z + vb.w * vb.w;
#pragma unroll
        for (int m = 16; m >= 1; m >>= 1) { sa += __shfl_xor(sa, m); sb += __shfl_xor(sb, m); }
        if ((tid & 31) == 0) { nA[row] = sa; nB[row] = sb; }
    }
    __syncthreads();

    const int lane = tid & 63;
    const int w    = tid >> 6;
    const int wr   = (w >> 1) << 5;
    const int wc   = (w & 1) << 5;
    const int lr   = lane & 15;
    const int kb   = lane >> 4;
    f32x4 acc[2][2] = {};
#pragma unroll
    for (int ks = 0; ks < 4; ++ks) {
        const int kc = (ks << 5) + (kb << 3);
        bf16x8 ahi[2], alo[2], bhi[2], blo[2];
#pragma unroll
        for (int i = 0; i < 2; ++i) {
            const int ar = (wr + (i << 4) + lr) * PK + kc;
            ahi[i] = *(const bf16x8*)(&sAhi[ar]);
            alo[i] = *(const bf16x8*)(&sAlo[ar]);
            const int br = (wc + (i << 4) + lr) * PK + kc;
            bhi[i] = *(const bf16x8*)(&sBhi[br]);
            blo[i] = *(const bf16x8*)(&sBlo[br]);
        }
#pragma unroll
        for (int i = 0; i < 2; ++i)
#pragma unroll
            for (int j = 0; j < 2; ++j) {
                acc[i][j] = __builtin_amdgcn_mfma_f32_16x16x32_bf16(ahi[i], bhi[j], acc[i][j], 0, 0, 0);
                acc[i][j] = __builtin_amdgcn_mfma_f32_16x16x32_bf16(ahi[i], blo[j], acc[i][j], 0, 0, 0);
                acc[i][j] = __builtin_amdgcn_mfma_f32_16x16x32_bf16(alo[i], bhi[j], acc[i][j], 0, 0, 0);
            }
    }
    float sg = fmaxf(sigp[0], 0.001f);
    const float c = -0.5f / (sg * sg);
#pragma unroll
    for (int i = 0; i < 2; ++i)
#pragma unroll
        for (int j = 0; j < 2; ++j)
#pragma unroll
            for (int r = 0; r < 4; ++r) {
                const int lrow = wr + (i << 4) + (kb << 2) + r;
                const int lcol = wc + (j << 4) + lr;
                float d2 = nA[lrow] + nB[lcol] - 2.0f * acc[i][j][r];
                d2 = fmaxf(d2, 0.0f);
                out[(size_t)(brow + lrow) * 4096 + (bcol + lcol)] = __expf(d2 * c);
            }
}

extern "C" void kernel_launch(void* const* d_in, const int* in_sizes, int n_in,
                              void* d_out, int out_size, void* d_ws, size_t ws_size,
                              hipStream_t stream) {
    const float* A    = (const float*)d_in[0];
    const float* Bm   = (const float*)d_in[1];
    const float* sigp = (const float*)d_in[2];
    float* out = (float*)d_out;

    if (ws_size >= WS_NEED) {
        char* ws = (char*)d_ws;
        short* Ahi = (short*)(ws + OFF_AHI);
        short* Alo = (short*)(ws + OFF_ALO);
        short* Bhi = (short*)(ws + OFF_BHI);
        short* Blo = (short*)(ws + OFF_BLO);
        float* nA  = (float*)(ws + OFF_NA);
        float* nB  = (float*)(ws + OFF_NB);

        dim3 pgrid((NROW_A + NROW_B) * 16 / 256, 1, 1);
        rbf_precompute<<<pgrid, 256, 0, stream>>>(A, Bm, Ahi, Alo, Bhi, Blo, nA, nB);

        // 512 persistent-ish blocks: 32 bcol tiles x 16 brow-groups (8 tiles each)
        rbf_mfma_persist<<<dim3(512, 1, 1), dim3(512, 1, 1), 0, stream>>>(
            Ahi, Alo, Bhi, Blo, nA, nB, sigp, out);
    } else {
        dim3 grid(4096 / 64, 16384 / 64, 1);
        rbf_mfma_fallback<<<grid, dim3(256, 1, 1), 0, stream>>>(A, Bm, sigp, out);
    }
}

// Round 6
// 60.113 us; speedup vs baseline: 3.5445x; 1.3278x over previous
//
#include <hip/hip_runtime.h>

// RBF kernel layer: K[b,n,m] = exp(-max(|a|^2+|b|^2-2ab,0)/(2*sigma^2))
// A: (8,2048,128) f32 -> flat (16384,128); B: (4096,128) f32; out (16384,4096) f32.
// Round 6: SINGLE-PASS bf16 (error budget audited: predicted absmax ~1e-28 vs
// threshold 1.1e-25). Halves LDS traffic/MFMA/staging; LDS 66KB -> 2 blocks/CU.
// Persistent blocks (B staged once, 8 brow tiles), T14 async A staging,
// operand-swapped MFMA -> float4 stores through L2, chunk-XOR LDS swizzle.

typedef __attribute__((ext_vector_type(8))) short bf16x8;
typedef __attribute__((ext_vector_type(4))) float f32x4;

#define NROW_A 16384
#define NROW_B 4096
#define D      128

// ws layout (bytes)
#define OFF_AHI 0u
#define OFF_BHI (OFF_AHI + NROW_A * D * 2u)          // 4,194,304
#define OFF_NA  (OFF_BHI + NROW_B * D * 2u)          // 5,242,880
#define OFF_NB  (OFF_NA + NROW_A * 4u)               // 5,308,416
#define WS_NEED (OFF_NB + NROW_B * 4u)               // 5,324,800

__device__ __forceinline__ short f2bf_hi(float x) {
    union { float f; unsigned u; } v; v.f = x;
    unsigned r = (v.u + 0x7fffu + ((v.u >> 16) & 1u)) >> 16;  // RN-even
    return (short)r;
}
__device__ __forceinline__ float bf2f(short h) {
    union { unsigned u; float f; } v; v.u = ((unsigned)(unsigned short)h) << 16;
    return v.f;
}

// ---------------- precompute: f32 -> bf16 + row norms ----------------
__global__ __launch_bounds__(256)
void rbf_precompute(const float* __restrict__ A, const float* __restrict__ Bm,
                    short* __restrict__ Ahi, short* __restrict__ Bhi,
                    float* __restrict__ nA, float* __restrict__ nB) {
    const int g   = blockIdx.x * 256 + threadIdx.x;
    const int row = g >> 4;
    const int c   = g & 15;

    const float* src; short* dhi; float* nrm; int r;
    if (row < NROW_A) {
        r = row; src = A + (size_t)r * D;
        dhi = Ahi + (size_t)r * D; nrm = nA + r;
    } else {
        r = row - NROW_A; src = Bm + (size_t)r * D;
        dhi = Bhi + (size_t)r * D; nrm = nB + r;
    }

    float4 v0 = *(const float4*)(src + c * 8);
    float4 v1 = *(const float4*)(src + c * 8 + 4);
    float f[8] = {v0.x, v0.y, v0.z, v0.w, v1.x, v1.y, v1.z, v1.w};

    bf16x8 hi;
    float ss = 0.0f;
#pragma unroll
    for (int e = 0; e < 8; ++e) {
        hi[e] = f2bf_hi(f[e]);
        ss += f[e] * f[e];
    }
    *(bf16x8*)(dhi + c * 8) = hi;

#pragma unroll
    for (int m = 1; m <= 8; m <<= 1) ss += __shfl_xor(ss, m);
    if (c == 0) *nrm = ss;
}

// ---------------- main: persistent 128x128 tiles, B resident ----------------
__global__ __launch_bounds__(512, 4)   // 4 waves/EU = 2 blocks/CU
void rbf_mfma_persist(const short* __restrict__ Ahi, const short* __restrict__ Bhi,
                      const float* __restrict__ nAg, const float* __restrict__ nBg,
                      const float* __restrict__ sigp, float* __restrict__ out) {
    __shared__ __align__(16) short sA[128 * 128];   // [row*128 + swz-chunk]
    __shared__ __align__(16) short sB[128 * 128];
    __shared__ __align__(16) float snA[128];
    __shared__ __align__(16) float snB[128];

    const int tid = threadIdx.x;
    const int bid = blockIdx.x;
    // XCD-chunked: xcd = bid&7 owns 4 bcol tiles; 16 brow-groups of 8 tiles.
    const int xcd = bid & 7;
    const int idx = bid >> 3;                 // 0..63
    const int bcol = ((xcd << 2) + (idx & 3)) << 7;
    const int bg   = idx >> 2;                // 0..15

    const int srow = tid >> 2;                // 0..127
    const int sc4  = tid & 3;

    // ---- prologue: stage B panel + snB; stage A(0) + snA ----
#pragma unroll
    for (int it = 0; it < 4; ++it) {
        const int c  = sc4 + (it << 2);
        const int cs = c ^ (srow & 15);
        *(bf16x8*)&sB[srow * 128 + cs * 8] =
            *(const bf16x8*)&Bhi[(size_t)(bcol + srow) * D + c * 8];
    }
    if (tid < 128) snB[tid] = nBg[bcol + tid];

    {
        const int brow0 = (bg << 3) << 7;
#pragma unroll
        for (int it = 0; it < 4; ++it) {
            const int c  = sc4 + (it << 2);
            const int cs = c ^ (srow & 15);
            *(bf16x8*)&sA[srow * 128 + cs * 8] =
                *(const bf16x8*)&Ahi[(size_t)(brow0 + srow) * D + c * 8];
        }
        if (tid >= 384) snA[tid - 384] = nAg[brow0 + tid - 384];
    }
    __syncthreads();

    const int lane = tid & 63;
    const int w    = tid >> 6;            // 0..7
    const int wr   = (w >> 1) << 5;       // 0/32/64/96
    const int wc   = (w & 1) << 6;        // 0/64
    const int lr   = lane & 15;
    const int kb   = lane >> 4;           // 0..3

    float sg = fmaxf(sigp[0], 0.001f);
    const float cc = -0.5f / (sg * sg);

    bf16x8 rh[4];
    float rn = 0.0f;

    for (int t = 0; t < 8; ++t) {
        const int browt = ((bg << 3) + t) << 7;

        // ---- issue A(t+1) global loads early (in flight under compute) ----
        if (t < 7) {
            const int brn = browt + 128;
#pragma unroll
            for (int it = 0; it < 4; ++it) {
                const int c = sc4 + (it << 2);
                rh[it] = *(const bf16x8*)&Ahi[(size_t)(brn + srow) * D + c * 8];
            }
            if (tid >= 384) rn = nAg[brn + tid - 384];
        }

        // ---- compute: single-pass MFMA, operand-swapped ----
        f32x4 acc[2][4] = {};
#pragma unroll
        for (int ks = 0; ks < 4; ++ks) {
            const int off = (((ks << 2) + kb) ^ lr) << 3;
            bf16x8 af[2], bf[4];
#pragma unroll
            for (int i = 0; i < 2; ++i)
                af[i] = *(const bf16x8*)&sA[(wr + (i << 4) + lr) * 128 + off];
#pragma unroll
            for (int j = 0; j < 4; ++j)
                bf[j] = *(const bf16x8*)&sB[(wc + (j << 4) + lr) * 128 + off];
#pragma unroll
            for (int i = 0; i < 2; ++i)
#pragma unroll
                for (int j = 0; j < 4; ++j)
                    // swapped: first operand = B fragment -> D "row" dim = out COLS
                    acc[i][j] = __builtin_amdgcn_mfma_f32_16x16x32_bf16(bf[j], af[i], acc[i][j], 0, 0, 0);
        }

        // ---- epilogue: lane owns 4 consecutive out cols -> float4 store ----
#pragma unroll
        for (int i = 0; i < 2; ++i) {
            const int orow = wr + (i << 4) + lr;      // out row = lane&15 dim
            const float na = snA[orow];
#pragma unroll
            for (int j = 0; j < 4; ++j) {
                const int ocol = wc + (j << 4) + (kb << 2);   // 4 consecutive cols
                const f32x4 nb = *(const f32x4*)&snB[ocol];
                f32x4 v;
#pragma unroll
                for (int r = 0; r < 4; ++r) {
                    float d2 = fmaxf(na + nb[r] - 2.0f * acc[i][j][r], 0.0f);
                    v[r] = __expf(d2 * cc);
                }
                *(f32x4*)(out + (size_t)(browt + orow) * 4096 + bcol + ocol) = v;
            }
        }

        __syncthreads();   // all waves done reading sA(t)/snA(t)

        if (t < 7) {
            // write-late: waitcnt here drains the (older) loads, not stores
#pragma unroll
            for (int it = 0; it < 4; ++it) {
                const int c  = sc4 + (it << 2);
                const int cs = c ^ (srow & 15);
                *(bf16x8*)&sA[srow * 128 + cs * 8] = rh[it];
            }
            if (tid >= 384) snA[tid - 384] = rn;
            __syncthreads();
        }
    }
}

// ---------------- fallback (self-contained, no ws; 3-pass split) ----------------
#define PK 136
__global__ __launch_bounds__(256, 2)
void rbf_mfma_fallback(const float* __restrict__ A, const float* __restrict__ Bm,
                       const float* __restrict__ sigp, float* __restrict__ out) {
    __shared__ __align__(16) short sAhi[64 * PK];
    __shared__ __align__(16) short sAlo[64 * PK];
    __shared__ __align__(16) short sBhi[64 * PK];
    __shared__ __align__(16) short sBlo[64 * PK];
    __shared__ float nA[64];
    __shared__ float nB[64];

    const int tid  = threadIdx.x;
    const int brow = blockIdx.y << 6;
    const int bcol = blockIdx.x << 6;

    const int r0 = tid >> 5;
    const int kq = (tid & 31) << 2;
#pragma unroll
    for (int it = 0; it < 8; ++it) {
        const int row = r0 + (it << 3);
        const float4 va = *(const float4*)(A  + (size_t)(brow + row) * 128 + kq);
        const float4 vb = *(const float4*)(Bm + (size_t)(bcol + row) * 128 + kq);
        short4 ha, la, hb, lb;
        ha.x = f2bf_hi(va.x); la.x = f2bf_hi(va.x - bf2f(ha.x));
        ha.y = f2bf_hi(va.y); la.y = f2bf_hi(va.y - bf2f(ha.y));
        ha.z = f2bf_hi(va.z); la.z = f2bf_hi(va.z - bf2f(ha.z));
        ha.w = f2bf_hi(va.w); la.w = f2bf_hi(va.w - bf2f(ha.w));
        hb.x = f2bf_hi(vb.x); lb.x = f2bf_hi(vb.x - bf2f(hb.x));
        hb.y = f2bf_hi(vb.y); lb.y = f2bf_hi(vb.y - bf2f(hb.y));
        hb.z = f2bf_hi(vb.z); lb.z = f2bf_hi(vb.z - bf2f(hb.z));
        hb.w = f2bf_hi(vb.w); lb.w = f2bf_hi(vb.w - bf2f(hb.w));
        const int idx = row * PK + kq;
        *(short4*)(&sAhi[idx]) = ha;
        *(short4*)(&sAlo[idx]) = la;
        *(short4*)(&sBhi[idx]) = hb;
        *(short4*)(&sBlo[idx]) = lb;
        float sa = va.x * va.x + va.y * va.y + va.z * va.z + va.w * va.w;
        float sb = vb.x * vb.x + vb.y * vb.y + vb.z * vb.z + vb.w * vb.w;
#pragma unroll
        for (int m = 16; m >= 1; m >>= 1) { sa += __shfl_xor(sa, m); sb += __shfl_xor(sb, m); }
        if ((tid & 31) == 0) { nA[row] = sa; nB[row] = sb; }
    }
    __syncthreads();

    const int lane = tid & 63;
    const int w    = tid >> 6;
    const int wr   = (w >> 1) << 5;
    const int wc   = (w & 1) << 5;
    const int lr   = lane & 15;
    const int kb   = lane >> 4;
    f32x4 acc[2][2] = {};
#pragma unroll
    for (int ks = 0; ks < 4; ++ks) {
        const int kc = (ks << 5) + (kb << 3);
        bf16x8 ahi[2], alo[2], bhi[2], blo[2];
#pragma unroll
        for (int i = 0; i < 2; ++i) {
            const int ar = (wr + (i << 4) + lr) * PK + kc;
            ahi[i] = *(const bf16x8*)(&sAhi[ar]);
            alo[i] = *(const bf16x8*)(&sAlo[ar]);
            const int br = (wc + (i << 4) + lr) * PK + kc;
            bhi[i] = *(const bf16x8*)(&sBhi[br]);
            blo[i] = *(const bf16x8*)(&sBlo[br]);
        }
#pragma unroll
        for (int i = 0; i < 2; ++i)
#pragma unroll
            for (int j = 0; j < 2; ++j) {
                acc[i][j] = __builtin_amdgcn_mfma_f32_16x16x32_bf16(ahi[i], bhi[j], acc[i][j], 0, 0, 0);
                acc[i][j] = __builtin_amdgcn_mfma_f32_16x16x32_bf16(ahi[i], blo[j], acc[i][j], 0, 0, 0);
                acc[i][j] = __builtin_amdgcn_mfma_f32_16x16x32_bf16(alo[i], bhi[j], acc[i][j], 0, 0, 0);
            }
    }
    float sg = fmaxf(sigp[0], 0.001f);
    const float c = -0.5f / (sg * sg);
#pragma unroll
    for (int i = 0; i < 2; ++i)
#pragma unroll
        for (int j = 0; j < 2; ++j)
#pragma unroll
            for (int r = 0; r < 4; ++r) {
                const int lrow = wr + (i << 4) + (kb << 2) + r;
                const int lcol = wc + (j << 4) + lr;
                float d2 = nA[lrow] + nB[lcol] - 2.0f * acc[i][j][r];
                d2 = fmaxf(d2, 0.0f);
                out[(size_t)(brow + lrow) * 4096 + (bcol + lcol)] = __expf(d2 * c);
            }
}

extern "C" void kernel_launch(void* const* d_in, const int* in_sizes, int n_in,
                              void* d_out, int out_size, void* d_ws, size_t ws_size,
                              hipStream_t stream) {
    const float* A    = (const float*)d_in[0];
    const float* Bm   = (const float*)d_in[1];
    const float* sigp = (const float*)d_in[2];
    float* out = (float*)d_out;

    if (ws_size >= WS_NEED) {
        char* ws = (char*)d_ws;
        short* Ahi = (short*)(ws + OFF_AHI);
        short* Bhi = (short*)(ws + OFF_BHI);
        float* nA  = (float*)(ws + OFF_NA);
        float* nB  = (float*)(ws + OFF_NB);

        dim3 pgrid((NROW_A + NROW_B) * 16 / 256, 1, 1);
        rbf_precompute<<<pgrid, 256, 0, stream>>>(A, Bm, Ahi, Bhi, nA, nB);

        // 512 persistent-ish blocks: 32 bcol tiles x 16 brow-groups (8 tiles each)
        rbf_mfma_persist<<<dim3(512, 1, 1), dim3(512, 1, 1), 0, stream>>>(
            Ahi, Bhi, nA, nB, sigp, out);
    } else {
        dim3 grid(4096 / 64, 16384 / 64, 1);
        rbf_mfma_fallback<<<grid, dim3(256, 1, 1), 0, stream>>>(A, Bm, sigp, out);
    }
}